// Round 1
// baseline (389.783 us; speedup 1.0000x reference)
//
#include <hip/hip_runtime.h>
#include <math.h>

#define NB 8
#define NT 2048
#define NE 1024
#define NH 64

// ---------------- Kernel 1: QKV projection, fp32 VALU ----------------
// grid 512 blocks x 256 threads. Block: 32 rows x 192 cols (q|k|v), K tiled by 32.
// Thread tile 4 rows x 6 cols. LDS holds x and W K-slices transposed ([k][row/col])
// so the inner loop does vector LDS reads (b128 for x, 3x b64 for w).
__global__ __launch_bounds__(256, 2) void qkv_proj_f32(
    const float* __restrict__ x,  const float* __restrict__ wq,
    const float* __restrict__ wk, const float* __restrict__ wv,
    float* __restrict__ qo, float* __restrict__ ko, float* __restrict__ vo)
{
    __shared__ float xsT[32][36];    // [kk][row], row-stride 144B (16B aligned)
    __shared__ float wsT[32][200];   // [kk][col], col c in [0,192)

    const int tid  = threadIdx.x;
    const int row0 = blockIdx.x * 32;
    const int tx   = tid & 31;       // col group: c0 = tx*6
    const int ty   = tid >> 5;       // row group: r0 = ty*4
    const int c0   = tx * 6;
    const int r0   = ty * 4;

    float acc[4][6];
#pragma unroll
    for (int i = 0; i < 4; ++i)
#pragma unroll
        for (int j = 0; j < 6; ++j) acc[i][j] = 0.f;

    for (int kt = 0; kt < NE; kt += 32) {
        // stage x tile: 32 rows x 32 k = 256 float4, 1 per thread (transposed scatter)
        {
            const int r  = tid >> 3;     // 0..31
            const int kq = tid & 7;      // float4 index within the 32-k slice
            float4 t = *(const float4*)(x + (size_t)(row0 + r) * NE + kt + kq * 4);
            xsT[kq*4+0][r] = t.x; xsT[kq*4+1][r] = t.y;
            xsT[kq*4+2][r] = t.z; xsT[kq*4+3][r] = t.w;
        }
        // stage w tile: 192 cols x 32 k = 1536 float4, 6 per thread
#pragma unroll
        for (int it = 0; it < 6; ++it) {
            const int f  = tid + it * 256;   // 0..1535
            const int c  = f >> 3;           // 0..191
            const int kq = f & 7;
            const float* wrow = (c < 64)  ? (wq + (size_t)c * NE)
                              : (c < 128) ? (wk + (size_t)(c - 64) * NE)
                              :             (wv + (size_t)(c - 128) * NE);
            float4 t = *(const float4*)(wrow + kt + kq * 4);
            wsT[kq*4+0][c] = t.x; wsT[kq*4+1][c] = t.y;
            wsT[kq*4+2][c] = t.z; wsT[kq*4+3][c] = t.w;
        }
        __syncthreads();

#pragma unroll
        for (int kk = 0; kk < 32; ++kk) {
            float4 xv = *(const float4*)&xsT[kk][r0];
            float2 w0 = *(const float2*)&wsT[kk][c0];
            float2 w1 = *(const float2*)&wsT[kk][c0 + 2];
            float2 w2 = *(const float2*)&wsT[kk][c0 + 4];
            const float xr[4] = {xv.x, xv.y, xv.z, xv.w};
            const float wr[6] = {w0.x, w0.y, w1.x, w1.y, w2.x, w2.y};
#pragma unroll
            for (int i = 0; i < 4; ++i)
#pragma unroll
                for (int j = 0; j < 6; ++j)
                    acc[i][j] = fmaf(xr[i], wr[j], acc[i][j]);
        }
        __syncthreads();
    }

    // write q/k/v (row-major [B*T][64])
#pragma unroll
    for (int i = 0; i < 4; ++i) {
        const int row = row0 + r0 + i;
#pragma unroll
        for (int j = 0; j < 6; ++j) {
            const int c = c0 + j;
            const float val = acc[i][j];
            if (c < 64)       qo[(size_t)row * NH + c]         = val;
            else if (c < 128) ko[(size_t)row * NH + (c - 64)]  = val;
            else              vo[(size_t)row * NH + (c - 128)] = val;
        }
    }
}

// ---------------- Kernel 2: flash attention, fp32 VALU ----------------
// grid (64, 8) x 256 threads. q-tile = 32 rows, kv-tile = 64.
// Thread tile: 2 q-rows x 4 kv-cols (S) / 2 q-rows x 4 head-dims (O).
// Heavy causal blocks (large qt) launch first via reversed blockIdx.x.
__global__ __launch_bounds__(256, 2) void flash_attn_f32(
    const float* __restrict__ q, const float* __restrict__ k,
    const float* __restrict__ v, const int* __restrict__ smp,
    float* __restrict__ out)
{
    __shared__ float qT[NH][36];   // [h][r]
    __shared__ float kT[NH][68];   // [h][c]
    __shared__ float vs[64][68];   // [c][h]
    __shared__ float ps[32][68];   // [r][c]

    const int tid = threadIdx.x;
    const int qt  = (int)(gridDim.x - 1) - (int)blockIdx.x;   // heavy first
    const int b   = blockIdx.y;
    const int qs  = qt * 32;
    const int sm  = smp[0];

    const int tx = tid & 15;       // kv-col group (*4) / head-dim group (*4)
    const int ty = tid >> 4;       // 0..15 -> q rows ty*2, ty*2+1

    const float* qb = q + (size_t)b * NT * NH;
    const float* kb = k + (size_t)b * NT * NH;
    const float* vb = v + (size_t)b * NT * NH;

    // stage q tile (32x64) transposed: 512 float4, 2 per thread
#pragma unroll
    for (int it = 0; it < 2; ++it) {
        const int f = tid + it * 256;
        const int r = f >> 4, hq = f & 15;
        float4 t = *(const float4*)(qb + (size_t)(qs + r) * NH + hq * 4);
        qT[hq*4+0][r] = t.x; qT[hq*4+1][r] = t.y;
        qT[hq*4+2][r] = t.z; qT[hq*4+3][r] = t.w;
    }

    float m_i[2] = {-INFINITY, -INFINITY};
    float l_i[2] = {0.f, 0.f};
    float o_acc[2][4] = {{0.f,0.f,0.f,0.f},{0.f,0.f,0.f,0.f}};

    const int ntiles = sm ? ((qs + 95) >> 6) : (NT >> 6);

    for (int jt = 0; jt < ntiles; ++jt) {
        const int js = jt << 6;
        __syncthreads();   // previous iteration's PV reads of vs/ps done
        // stage k (transposed) and v tiles: 64x64 each
#pragma unroll
        for (int it = 0; it < 4; ++it) {
            const int f = tid + it * 256;
            const int r = f >> 4, hq = f & 15;
            float4 t = *(const float4*)(kb + (size_t)(js + r) * NH + hq * 4);
            kT[hq*4+0][r] = t.x; kT[hq*4+1][r] = t.y;
            kT[hq*4+2][r] = t.z; kT[hq*4+3][r] = t.w;
            float4 u = *(const float4*)(vb + (size_t)(js + r) * NH + hq * 4);
            *(float4*)&vs[r][hq*4] = u;
        }
        __syncthreads();

        // S = (q k^T) * sqrt(64)
        float s[2][4] = {{0.f,0.f,0.f,0.f},{0.f,0.f,0.f,0.f}};
#pragma unroll 8
        for (int kk = 0; kk < NH; ++kk) {
            float2 qv  = *(const float2*)&qT[kk][ty * 2];
            float4 kv4 = *(const float4*)&kT[kk][tx * 4];
            s[0][0] = fmaf(qv.x, kv4.x, s[0][0]);
            s[0][1] = fmaf(qv.x, kv4.y, s[0][1]);
            s[0][2] = fmaf(qv.x, kv4.z, s[0][2]);
            s[0][3] = fmaf(qv.x, kv4.w, s[0][3]);
            s[1][0] = fmaf(qv.y, kv4.x, s[1][0]);
            s[1][1] = fmaf(qv.y, kv4.y, s[1][1]);
            s[1][2] = fmaf(qv.y, kv4.z, s[1][2]);
            s[1][3] = fmaf(qv.y, kv4.w, s[1][3]);
        }
#pragma unroll
        for (int i = 0; i < 2; ++i)
#pragma unroll
            for (int j = 0; j < 4; ++j) s[i][j] *= 8.0f;

        // causal mask (only tiles touching the diagonal)
        if (sm && (js + 63 > qs)) {
#pragma unroll
            for (int i = 0; i < 2; ++i) {
                const int row = qs + ty * 2 + i;
#pragma unroll
                for (int j = 0; j < 4; ++j) {
                    const int col = js + tx * 4 + j;
                    if (col > row) s[i][j] = -INFINITY;
                }
            }
        }

        // online softmax update (row stats across the 16 tx lanes)
        float rm[2], mn[2], cf[2], rs[2], p[2][4];
#pragma unroll
        for (int i = 0; i < 2; ++i)
            rm[i] = fmaxf(fmaxf(s[i][0], s[i][1]), fmaxf(s[i][2], s[i][3]));
#pragma unroll
        for (int off = 1; off < 16; off <<= 1) {
            rm[0] = fmaxf(rm[0], __shfl_xor(rm[0], off));
            rm[1] = fmaxf(rm[1], __shfl_xor(rm[1], off));
        }
#pragma unroll
        for (int i = 0; i < 2; ++i) {
            mn[i] = fmaxf(m_i[i], rm[i]);
            cf[i] = __expf(m_i[i] - mn[i]);
            rs[i] = 0.f;
#pragma unroll
            for (int j = 0; j < 4; ++j) {
                p[i][j] = __expf(s[i][j] - mn[i]);
                rs[i] += p[i][j];
            }
        }
#pragma unroll
        for (int off = 1; off < 16; off <<= 1) {
            rs[0] += __shfl_xor(rs[0], off);
            rs[1] += __shfl_xor(rs[1], off);
        }
#pragma unroll
        for (int i = 0; i < 2; ++i) {
            l_i[i] = l_i[i] * cf[i] + rs[i];
            m_i[i] = mn[i];
#pragma unroll
            for (int j = 0; j < 4; ++j) o_acc[i][j] *= cf[i];
        }

        *(float4*)&ps[ty*2+0][tx*4] = make_float4(p[0][0], p[0][1], p[0][2], p[0][3]);
        *(float4*)&ps[ty*2+1][tx*4] = make_float4(p[1][0], p[1][1], p[1][2], p[1][3]);
        __syncthreads();

        // O += P @ V
#pragma unroll 4
        for (int k4 = 0; k4 < 16; ++k4) {
            float4 p0 = *(const float4*)&ps[ty*2+0][k4*4];
            float4 p1 = *(const float4*)&ps[ty*2+1][k4*4];
            const float pr0[4] = {p0.x, p0.y, p0.z, p0.w};
            const float pr1[4] = {p1.x, p1.y, p1.z, p1.w};
#pragma unroll
            for (int c = 0; c < 4; ++c) {
                float4 vv = *(const float4*)&vs[k4*4+c][tx*4];
                o_acc[0][0] = fmaf(pr0[c], vv.x, o_acc[0][0]);
                o_acc[0][1] = fmaf(pr0[c], vv.y, o_acc[0][1]);
                o_acc[0][2] = fmaf(pr0[c], vv.z, o_acc[0][2]);
                o_acc[0][3] = fmaf(pr0[c], vv.w, o_acc[0][3]);
                o_acc[1][0] = fmaf(pr1[c], vv.x, o_acc[1][0]);
                o_acc[1][1] = fmaf(pr1[c], vv.y, o_acc[1][1]);
                o_acc[1][2] = fmaf(pr1[c], vv.z, o_acc[1][2]);
                o_acc[1][3] = fmaf(pr1[c], vv.w, o_acc[1][3]);
            }
        }
    }

    // normalize and write out (fp32, (B,T,H))
#pragma unroll
    for (int i = 0; i < 2; ++i) {
        const float inv = 1.0f / l_i[i];
        float4 o = make_float4(o_acc[i][0]*inv, o_acc[i][1]*inv,
                               o_acc[i][2]*inv, o_acc[i][3]*inv);
        *(float4*)(out + ((size_t)b * NT + qs + ty*2 + i) * NH + tx * 4) = o;
    }
}

extern "C" void kernel_launch(void* const* d_in, const int* in_sizes, int n_in,
                              void* d_out, int out_size, void* d_ws, size_t ws_size,
                              hipStream_t stream)
{
    const float* x  = (const float*)d_in[0];
    const float* wq = (const float*)d_in[1];
    const float* wk = (const float*)d_in[2];
    const float* wv = (const float*)d_in[3];
    const int*   sm = (const int*)d_in[4];
    float* out = (float*)d_out;

    float* qws = (float*)d_ws;                    // 16384*64 fp32
    float* kws = qws + (size_t)NB * NT * NH;
    float* vws = kws + (size_t)NB * NT * NH;

    qkv_proj_f32<<<dim3((NB * NT) / 32), 256, 0, stream>>>(x, wq, wk, wv, qws, kws, vws);
    flash_attn_f32<<<dim3(NT / 32, NB), 256, 0, stream>>>(qws, kws, vws, sm, out);
}

// Round 2
// 242.648 us; speedup vs baseline: 1.6064x; 1.6064x over previous
//
#include <hip/hip_runtime.h>
#include <math.h>

#define NB 8
#define NT 2048
#define NE 1024
#define NH 64

typedef __attribute__((ext_vector_type(8))) short bh8;   // 8 x bf16 (bit pattern in shorts)
typedef __attribute__((ext_vector_type(4))) float f4;    // MFMA accumulator

typedef unsigned short u16;

__device__ __forceinline__ u16 bf16rn(float f) {
    unsigned u = __float_as_uint(f);
    u += 0x7FFFu + ((u >> 16) & 1u);      // round-to-nearest-even
    return (u16)(u >> 16);
}
__device__ __forceinline__ float bf16f(u16 h) {
    return __uint_as_float(((unsigned)h) << 16);
}

// ---------------- Kernel 0: W -> (hi, lo) bf16, concatenated [192][1024] ----
__global__ void wprep(const float* __restrict__ wq, const float* __restrict__ wk,
                      const float* __restrict__ wv,
                      u16* __restrict__ whi, u16* __restrict__ wlo)
{
    const int row = blockIdx.x;                       // 0..191
    const int k0  = threadIdx.x * 4;                  // 256 thr * 4 = 1024
    const float* src = (row < 64)  ? (wq + (size_t)row * NE)
                     : (row < 128) ? (wk + (size_t)(row - 64) * NE)
                     :               (wv + (size_t)(row - 128) * NE);
    float4 v = *(const float4*)(src + k0);
    ushort4 h, l;
    h.x = bf16rn(v.x); l.x = bf16rn(v.x - bf16f(h.x));
    h.y = bf16rn(v.y); l.y = bf16rn(v.y - bf16f(h.y));
    h.z = bf16rn(v.z); l.z = bf16rn(v.z - bf16f(h.z));
    h.w = bf16rn(v.w); l.w = bf16rn(v.w - bf16f(h.w));
    *(ushort4*)(whi + (size_t)row * NE + k0) = h;
    *(ushort4*)(wlo + (size_t)row * NE + k0) = l;
}

// ---------------- Kernel 1: QKV projection via split-bf16 MFMA ---------------
// C[16384][192] = X[16384][1024] * W^T.  Block: 64 rows x 192 cols, BK=32.
// 4 waves, wave w handles cols [48w, 48w+48) x all 64 rows (4 m-sub x 3 n-sub).
// Split: C = xh*wh + xh*wl + xl*wh  (lo*lo dropped, ~2^-18 rel).
// Epilogue: q scaled by 8 (sqrt(H) folded), split to hi/lo; k split; v -> bf16
// written transposed per batch with 4x16 in-tile permutation for K2's PV reads.
__global__ __launch_bounds__(256, 1) void qkv_mfma(
    const float* __restrict__ x, const u16* __restrict__ whi_, const u16* __restrict__ wlo_,
    u16* __restrict__ qhi, u16* __restrict__ qlo,
    u16* __restrict__ khi, u16* __restrict__ klo, u16* __restrict__ vtp)
{
    __shared__ u16 xh[64][40], xl[64][40];     // row stride 80B (pad: bank-safe)
    __shared__ u16 wh[192][40], wl[192][40];

    const int tid  = threadIdx.x;
    const int wid  = tid >> 6;
    const int lane = tid & 63;
    const int t15  = lane & 15, t4 = lane >> 4;
    const int row0 = blockIdx.x * 64;

    const f4 fzero = {0.f, 0.f, 0.f, 0.f};
    f4 acc[4][3];
#pragma unroll
    for (int m = 0; m < 4; ++m)
#pragma unroll
        for (int n = 0; n < 3; ++n) acc[m][n] = fzero;

    for (int kt = 0; kt < NE; kt += 32) {
        __syncthreads();
        // stage X tile (64x32 fp32 -> hi/lo bf16): 512 float4, 2/thread
#pragma unroll
        for (int it = 0; it < 2; ++it) {
            const int f = tid + it * 256;
            const int r = f >> 3, sg = f & 7;
            float4 v = *(const float4*)(x + (size_t)(row0 + r) * NE + kt + sg * 4);
            ushort4 h, l;
            h.x = bf16rn(v.x); l.x = bf16rn(v.x - bf16f(h.x));
            h.y = bf16rn(v.y); l.y = bf16rn(v.y - bf16f(h.y));
            h.z = bf16rn(v.z); l.z = bf16rn(v.z - bf16f(h.z));
            h.w = bf16rn(v.w); l.w = bf16rn(v.w - bf16f(h.w));
            *(ushort4*)&xh[r][sg * 4] = h;
            *(ushort4*)&xl[r][sg * 4] = l;
        }
        // stage W tile (192x32 bf16 hi+lo): 768 uint4 per buffer, 3/thread
#pragma unroll
        for (int it = 0; it < 3; ++it) {
            const int f = tid + it * 256;
            const int r = f >> 2, sg = f & 3;
            *(uint4*)&wh[r][sg * 8] = *(const uint4*)(whi_ + (size_t)r * NE + kt + sg * 8);
            *(uint4*)&wl[r][sg * 8] = *(const uint4*)(wlo_ + (size_t)r * NE + kt + sg * 8);
        }
        __syncthreads();

        bh8 ah[4], al[4];
#pragma unroll
        for (int m = 0; m < 4; ++m) {
            ah[m] = *(const bh8*)&xh[m * 16 + t15][t4 * 8];
            al[m] = *(const bh8*)&xl[m * 16 + t15][t4 * 8];
        }
#pragma unroll
        for (int n = 0; n < 3; ++n) {
            const int c = wid * 48 + n * 16 + t15;
            bh8 bh = *(const bh8*)&wh[c][t4 * 8];
            bh8 bl = *(const bh8*)&wl[c][t4 * 8];
#pragma unroll
            for (int m = 0; m < 4; ++m) {
                acc[m][n] = __builtin_amdgcn_mfma_f32_16x16x32_bf16(ah[m], bh, acc[m][n], 0, 0, 0);
                acc[m][n] = __builtin_amdgcn_mfma_f32_16x16x32_bf16(ah[m], bl, acc[m][n], 0, 0, 0);
                acc[m][n] = __builtin_amdgcn_mfma_f32_16x16x32_bf16(al[m], bh, acc[m][n], 0, 0, 0);
            }
        }
    }

    // epilogue: D layout col=lane&15, row=(lane>>4)*4+reg  [m89-verified]
#pragma unroll
    for (int m = 0; m < 4; ++m) {
#pragma unroll
        for (int n = 0; n < 3; ++n) {
            const int col = wid * 48 + n * 16 + t15;
#pragma unroll
            for (int r = 0; r < 4; ++r) {
                const int row = row0 + m * 16 + t4 * 4 + r;
                float v = acc[m][n][r];
                if (col < 64) {
                    v *= 8.0f;                         // sqrt(head_size) folded into q
                    const u16 h = bf16rn(v);
                    qhi[(size_t)row * NH + col] = h;
                    qlo[(size_t)row * NH + col] = bf16rn(v - bf16f(h));
                } else if (col < 128) {
                    const u16 h = bf16rn(v);
                    khi[(size_t)row * NH + (col - 64)] = h;
                    klo[(size_t)row * NH + (col - 64)] = bf16rn(v - bf16f(h));
                } else {
                    const int b   = row >> 11;
                    const int tok = row & (NT - 1);
                    const int c   = tok & 63;
                    const int tp  = (tok & ~63) | ((c & 15) * 4 + (c >> 4)); // p(c)
                    vtp[((size_t)b * NH + (col - 128)) * NT + tp] = bf16rn(v);
                }
            }
        }
    }
}

// ---------------- Kernel 2: MFMA flash attention -----------------------------
// grid (32, 8) x 256 thr. q-tile 64 (wave w: rows 16w..16w+15), kv-tile 64.
// S = (8q)k^T via split MFMA (qh*kh + qh*kl + ql*kh); online softmax in regs;
// P -> LDS bf16 in permuted-col order p = t*4+n matching vtp; PV plain bf16.
__global__ __launch_bounds__(256, 1) void attn_mfma(
    const u16* __restrict__ qhi, const u16* __restrict__ qlo,
    const u16* __restrict__ khi, const u16* __restrict__ klo,
    const u16* __restrict__ vtp, const int* __restrict__ smp,
    float* __restrict__ out)
{
    __shared__ u16 kh[64][72], kl[64][72], vt[64][72], ps[64][72];  // stride 144B

    const int tid  = threadIdx.x;
    const int wid  = tid >> 6;
    const int lane = tid & 63;
    const int t15  = lane & 15, t4 = lane >> 4;
    const int qt   = (int)gridDim.x - 1 - (int)blockIdx.x;   // heavy first
    const int b    = blockIdx.y;
    const int qs   = qt * 64;
    const int sm   = smp[0];

    const size_t bb = (size_t)b * NT;

    // hoist Q fragments (A-frag: lane holds row=l&15, k=(l>>4)*8+j)
    bh8 qh[2], ql[2];
#pragma unroll
    for (int ks = 0; ks < 2; ++ks) {
        const size_t off = (bb + qs + wid * 16 + t15) * NH + ks * 32 + t4 * 8;
        qh[ks] = *(const bh8*)(qhi + off);
        ql[ks] = *(const bh8*)(qlo + off);
    }

    const f4 fzero = {0.f, 0.f, 0.f, 0.f};
    f4 o[4];
    float m_i[4], l_i[4];
#pragma unroll
    for (int i = 0; i < 4; ++i) { o[i] = fzero; m_i[i] = -INFINITY; l_i[i] = 0.f; }

    const int ntiles = sm ? (qt + 1) : (NT / 64);

    for (int jt = 0; jt < ntiles; ++jt) {
        const int js = jt * 64;
        __syncthreads();                       // prev iter done with kh/kl/vt
        // stage K hi/lo + V^T: 512 uint4 per buffer, 2/thread each
#pragma unroll
        for (int it = 0; it < 2; ++it) {
            const int f = tid + it * 256;
            const int r = f >> 3, sg = f & 7;
            *(uint4*)&kh[r][sg * 8] = *(const uint4*)(khi + (bb + js + r) * NH + sg * 8);
            *(uint4*)&kl[r][sg * 8] = *(const uint4*)(klo + (bb + js + r) * NH + sg * 8);
            *(uint4*)&vt[r][sg * 8] = *(const uint4*)(vtp + ((size_t)b * NH + r) * NT + js + sg * 8);
        }
        __syncthreads();

        // S = (8q) k^T (split)
        f4 s[4];
#pragma unroll
        for (int n = 0; n < 4; ++n) s[n] = fzero;
#pragma unroll
        for (int n = 0; n < 4; ++n) {
#pragma unroll
            for (int ks = 0; ks < 2; ++ks) {
                bh8 bh = *(const bh8*)&kh[n * 16 + t15][ks * 32 + t4 * 8];
                bh8 bl = *(const bh8*)&kl[n * 16 + t15][ks * 32 + t4 * 8];
                s[n] = __builtin_amdgcn_mfma_f32_16x16x32_bf16(qh[ks], bh, s[n], 0, 0, 0);
                s[n] = __builtin_amdgcn_mfma_f32_16x16x32_bf16(qh[ks], bl, s[n], 0, 0, 0);
                s[n] = __builtin_amdgcn_mfma_f32_16x16x32_bf16(ql[ks], bh, s[n], 0, 0, 0);
            }
        }

        // causal mask — only the diagonal tile
        if (sm && jt == qt) {
#pragma unroll
            for (int n = 0; n < 4; ++n) {
                const int col = n * 16 + t15;
#pragma unroll
                for (int r = 0; r < 4; ++r)
                    if (col > wid * 16 + t4 * 4 + r) s[n][r] = -INFINITY;
            }
        }

        // online softmax per row (reg r); stats across 16-lane groups
#pragma unroll
        for (int r = 0; r < 4; ++r) {
            float rm = fmaxf(fmaxf(s[0][r], s[1][r]), fmaxf(s[2][r], s[3][r]));
            rm = fmaxf(rm, __shfl_xor(rm, 1));
            rm = fmaxf(rm, __shfl_xor(rm, 2));
            rm = fmaxf(rm, __shfl_xor(rm, 4));
            rm = fmaxf(rm, __shfl_xor(rm, 8));
            const float mn = fmaxf(m_i[r], rm);
            const float cf = __expf(m_i[r] - mn);
            const float p0 = __expf(s[0][r] - mn);
            const float p1 = __expf(s[1][r] - mn);
            const float p2 = __expf(s[2][r] - mn);
            const float p3 = __expf(s[3][r] - mn);
            float rs = p0 + p1 + p2 + p3;
            rs += __shfl_xor(rs, 1);
            rs += __shfl_xor(rs, 2);
            rs += __shfl_xor(rs, 4);
            rs += __shfl_xor(rs, 8);
            l_i[r] = l_i[r] * cf + rs;
            m_i[r] = mn;
#pragma unroll
            for (int hs = 0; hs < 4; ++hs) o[hs][r] *= cf;
            ushort4 pw;
            pw.x = bf16rn(p0); pw.y = bf16rn(p1); pw.z = bf16rn(p2); pw.w = bf16rn(p3);
            // P'[row][p], p = t15*4 + n  (matches vtp permutation c(p)=(p&3)*16+(p>>2))
            *(ushort4*)&ps[wid * 16 + t4 * 4 + r][t15 * 4] = pw;
        }

        // O += P' V'   (k-dim runs over permuted index p; sum invariant)
#pragma unroll
        for (int ks = 0; ks < 2; ++ks) {
            bh8 pa = *(const bh8*)&ps[wid * 16 + t15][ks * 32 + t4 * 8];
#pragma unroll
            for (int hs = 0; hs < 4; ++hs) {
                bh8 bv = *(const bh8*)&vt[hs * 16 + t15][ks * 32 + t4 * 8];
                o[hs] = __builtin_amdgcn_mfma_f32_16x16x32_bf16(pa, bv, o[hs], 0, 0, 0);
            }
        }
    }

    // normalize + write fp32 out (coalesced 256B per (hs, r) across the wave)
#pragma unroll
    for (int r = 0; r < 4; ++r) {
        const float inv = 1.0f / l_i[r];
        const size_t rowoff = (bb + qs + wid * 16 + t4 * 4 + r) * NH;
#pragma unroll
        for (int hs = 0; hs < 4; ++hs)
            out[rowoff + hs * 16 + t15] = o[hs][r] * inv;
    }
}

extern "C" void kernel_launch(void* const* d_in, const int* in_sizes, int n_in,
                              void* d_out, int out_size, void* d_ws, size_t ws_size,
                              hipStream_t stream)
{
    const float* x  = (const float*)d_in[0];
    const float* wq = (const float*)d_in[1];
    const float* wk = (const float*)d_in[2];
    const float* wv = (const float*)d_in[3];
    const int*   sm = (const int*)d_in[4];
    float* out = (float*)d_out;

    u16* whi = (u16*)d_ws;                       // [192][1024]
    u16* wlo = whi + (size_t)192 * NE;
    u16* qhi = wlo + (size_t)192 * NE;           // [B*T][64] each below
    u16* qlo = qhi + (size_t)NB * NT * NH;
    u16* khi = qlo + (size_t)NB * NT * NH;
    u16* klo = khi + (size_t)NB * NT * NH;
    u16* vtp = klo + (size_t)NB * NT * NH;       // [B][64][2048] permuted

    wprep<<<dim3(192), 256, 0, stream>>>(wq, wk, wv, whi, wlo);
    qkv_mfma<<<dim3((NB * NT) / 64), 256, 0, stream>>>(x, whi, wlo, qhi, qlo, khi, klo, vtp);
    attn_mfma<<<dim3(NT / 64, NB), 256, 0, stream>>>(qhi, qlo, khi, klo, vtp, sm, out);
}

// Round 3
// 168.392 us; speedup vs baseline: 2.3147x; 1.4410x over previous
//
#include <hip/hip_runtime.h>
#include <math.h>

#define NB 8
#define NT 2048
#define NE 1024
#define NH 64

typedef __attribute__((ext_vector_type(8))) short bh8;   // 8 x bf16 bits
typedef __attribute__((ext_vector_type(4))) float f4;    // MFMA accumulator

typedef unsigned short u16;

__device__ __forceinline__ u16 bf16rn(float f) {
    unsigned u = __float_as_uint(f);
    u += 0x7FFFu + ((u >> 16) & 1u);      // round-to-nearest-even
    return (u16)(u >> 16);
}
__device__ __forceinline__ float bf16f(u16 h) {
    return __uint_as_float(((unsigned)h) << 16);
}

// ---------------- Kernel 0: W -> (hi, lo) bf16, concatenated [192][1024] ----
__global__ void wprep(const float* __restrict__ wq, const float* __restrict__ wk,
                      const float* __restrict__ wv,
                      u16* __restrict__ whi, u16* __restrict__ wlo)
{
    const int row = blockIdx.x;                       // 0..191
    const int k0  = threadIdx.x * 4;
    const float* src = (row < 64)  ? (wq + (size_t)row * NE)
                     : (row < 128) ? (wk + (size_t)(row - 64) * NE)
                     :               (wv + (size_t)(row - 128) * NE);
    float4 v = *(const float4*)(src + k0);
    ushort4 h, l;
    h.x = bf16rn(v.x); l.x = bf16rn(v.x - bf16f(h.x));
    h.y = bf16rn(v.y); l.y = bf16rn(v.y - bf16f(h.y));
    h.z = bf16rn(v.z); l.z = bf16rn(v.z - bf16f(h.z));
    h.w = bf16rn(v.w); l.w = bf16rn(v.w - bf16f(h.w));
    *(ushort4*)(whi + (size_t)row * NE + k0) = h;
    *(ushort4*)(wlo + (size_t)row * NE + k0) = l;
}

// ---------------- Kernel 1: QKV projection via split-bf16 MFMA ---------------
// 512 blocks x 256 thr. Block: 32 rows x 192 cols, BK=64 (16 k-steps).
// Wave w: cols [48w,48w+48) x 32 rows (2 m-frags x 3 n-frags).
// C = xh*wh + xh*wl + xl*wh (lo*lo dropped).
__global__ __launch_bounds__(256, 2) void qkv_mfma(
    const float* __restrict__ x, const u16* __restrict__ whi_, const u16* __restrict__ wlo_,
    u16* __restrict__ qhi, u16* __restrict__ qlo,
    u16* __restrict__ khi, u16* __restrict__ klo, u16* __restrict__ vtp)
{
    __shared__ u16 xh[32][72], xl[32][72];     // row stride 144B
    __shared__ u16 wh[192][72], wl[192][72];

    const int tid  = threadIdx.x;
    const int wid  = tid >> 6;
    const int lane = tid & 63;
    const int t15  = lane & 15, t4 = lane >> 4;
    const int row0 = blockIdx.x * 32;

    const f4 fzero = {0.f, 0.f, 0.f, 0.f};
    f4 acc[2][3];
#pragma unroll
    for (int m = 0; m < 2; ++m)
#pragma unroll
        for (int n = 0; n < 3; ++n) acc[m][n] = fzero;

    for (int kt = 0; kt < NE; kt += 64) {
        __syncthreads();
        // stage X tile (32x64 fp32 -> hi/lo bf16): 512 float4, 2/thread
#pragma unroll
        for (int it = 0; it < 2; ++it) {
            const int f = tid + it * 256;
            const int r = f >> 4, sg = f & 15;
            float4 v = *(const float4*)(x + (size_t)(row0 + r) * NE + kt + sg * 4);
            ushort4 h, l;
            h.x = bf16rn(v.x); l.x = bf16rn(v.x - bf16f(h.x));
            h.y = bf16rn(v.y); l.y = bf16rn(v.y - bf16f(h.y));
            h.z = bf16rn(v.z); l.z = bf16rn(v.z - bf16f(h.z));
            h.w = bf16rn(v.w); l.w = bf16rn(v.w - bf16f(h.w));
            *(ushort4*)&xh[r][sg * 4] = h;
            *(ushort4*)&xl[r][sg * 4] = l;
        }
        // stage W tile (192x64 bf16 hi+lo): 1536 uint4 per buffer, 6/thread
#pragma unroll
        for (int it = 0; it < 6; ++it) {
            const int f = tid + it * 256;
            const int r = f >> 3, sg = f & 7;
            *(uint4*)&wh[r][sg * 8] = *(const uint4*)(whi_ + (size_t)r * NE + kt + sg * 8);
            *(uint4*)&wl[r][sg * 8] = *(const uint4*)(wlo_ + (size_t)r * NE + kt + sg * 8);
        }
        __syncthreads();

#pragma unroll
        for (int ks = 0; ks < 2; ++ks) {
            bh8 ah[2], al[2];
#pragma unroll
            for (int m = 0; m < 2; ++m) {
                ah[m] = *(const bh8*)&xh[m * 16 + t15][ks * 32 + t4 * 8];
                al[m] = *(const bh8*)&xl[m * 16 + t15][ks * 32 + t4 * 8];
            }
#pragma unroll
            for (int n = 0; n < 3; ++n) {
                const int c = wid * 48 + n * 16 + t15;
                bh8 bhv = *(const bh8*)&wh[c][ks * 32 + t4 * 8];
                bh8 blv = *(const bh8*)&wl[c][ks * 32 + t4 * 8];
#pragma unroll
                for (int m = 0; m < 2; ++m) {
                    acc[m][n] = __builtin_amdgcn_mfma_f32_16x16x32_bf16(ah[m], bhv, acc[m][n], 0, 0, 0);
                    acc[m][n] = __builtin_amdgcn_mfma_f32_16x16x32_bf16(ah[m], blv, acc[m][n], 0, 0, 0);
                    acc[m][n] = __builtin_amdgcn_mfma_f32_16x16x32_bf16(al[m], bhv, acc[m][n], 0, 0, 0);
                }
            }
        }
    }

    // epilogue: D layout col=lane&15, row=(lane>>4)*4+reg
#pragma unroll
    for (int m = 0; m < 2; ++m) {
#pragma unroll
        for (int n = 0; n < 3; ++n) {
            const int col = wid * 48 + n * 16 + t15;
#pragma unroll
            for (int r = 0; r < 4; ++r) {
                const int row = row0 + m * 16 + t4 * 4 + r;
                float v = acc[m][n][r];
                if (col < 64) {
                    v *= 8.0f;                         // sqrt(head_size) folded into q
                    const u16 h = bf16rn(v);
                    qhi[(size_t)row * NH + col] = h;
                    qlo[(size_t)row * NH + col] = bf16rn(v - bf16f(h));
                } else if (col < 128) {
                    const u16 h = bf16rn(v);
                    khi[(size_t)row * NH + (col - 64)] = h;
                    klo[(size_t)row * NH + (col - 64)] = bf16rn(v - bf16f(h));
                } else {
                    const int b   = row >> 11;
                    const int tok = row & (NT - 1);
                    const int c   = tok & 63;
                    const int tp  = (tok & ~63) | ((c & 15) * 4 + (c >> 4)); // p(c)
                    vtp[((size_t)b * NH + (col - 128)) * NT + tp] = bf16rn(v);
                }
            }
        }
    }
}

// ---------------- Kernel 2: MFMA flash attention, KV-split -------------------
// grid (80, 8) x 256 thr. q-tile 64 (wave w: rows 16w..16w+15), kv-tile 64.
// Per (b,qt): nch=(qt+8)/8 chunks over the kv range, one block each.
// nch==1 -> write out directly; else write unnormalized (o, m, l) partials.
__global__ __launch_bounds__(256, 2) void attn_mfma(
    const u16* __restrict__ qhi, const u16* __restrict__ qlo,
    const u16* __restrict__ khi, const u16* __restrict__ klo,
    const u16* __restrict__ vtp, const int* __restrict__ smp,
    float* __restrict__ out,
    float* __restrict__ po, float* __restrict__ pm, float* __restrict__ pl)
{
    __shared__ u16 kh[64][72], kl[64][72], vt[64][72], ps[64][72];  // stride 144B

    const int tid  = threadIdx.x;
    const int wid  = tid >> 6;
    const int lane = tid & 63;
    const int t15  = lane & 15, t4 = lane >> 4;
    const int b    = blockIdx.y;
    const int u    = 79 - (int)blockIdx.x;       // heavy chunks dispatch first
    int qt, c;
    if (u < 8)       { qt = u;                   c = 0; }
    else if (u < 24) { qt = 8  + ((u - 8) >> 1); c = (u - 8) & 1; }
    else if (u < 48) { qt = 16 + (u - 24) / 3;   c = (u - 24) % 3; }
    else             { qt = 24 + ((u - 48) >> 2); c = (u - 48) & 3; }
    const int nch   = (qt + 8) >> 3;
    const int sm    = smp[0];
    const int total = sm ? (qt + 1) : (NT / 64);
    const int jt0   = c * total / nch;
    const int jt1   = (c + 1) * total / nch;
    const int qs    = qt * 64;

    const size_t bb = (size_t)b * NT;

    // hoist Q fragments (A-frag: lane holds row=l&15, k=(l>>4)*8+j)
    bh8 qh[2], ql[2];
#pragma unroll
    for (int ks = 0; ks < 2; ++ks) {
        const size_t off = (bb + qs + wid * 16 + t15) * NH + ks * 32 + t4 * 8;
        qh[ks] = *(const bh8*)(qhi + off);
        ql[ks] = *(const bh8*)(qlo + off);
    }

    const f4 fzero = {0.f, 0.f, 0.f, 0.f};
    f4 o[4];
    float m_i[4], l_i[4];
#pragma unroll
    for (int i = 0; i < 4; ++i) { o[i] = fzero; m_i[i] = -INFINITY; l_i[i] = 0.f; }

    for (int jt = jt0; jt < jt1; ++jt) {
        const int js = jt * 64;
        __syncthreads();                       // prev iter done with kh/kl/vt/ps
        // stage K hi/lo + V^T: 512 uint4 per buffer, 2/thread each
#pragma unroll
        for (int it = 0; it < 2; ++it) {
            const int f = tid + it * 256;
            const int r = f >> 3, sg = f & 7;
            *(uint4*)&kh[r][sg * 8] = *(const uint4*)(khi + (bb + js + r) * NH + sg * 8);
            *(uint4*)&kl[r][sg * 8] = *(const uint4*)(klo + (bb + js + r) * NH + sg * 8);
            *(uint4*)&vt[r][sg * 8] = *(const uint4*)(vtp + ((size_t)b * NH + r) * NT + js + sg * 8);
        }
        __syncthreads();

        // S = (8q) k^T (split)
        f4 s[4];
#pragma unroll
        for (int n = 0; n < 4; ++n) s[n] = fzero;
#pragma unroll
        for (int n = 0; n < 4; ++n) {
#pragma unroll
            for (int ks = 0; ks < 2; ++ks) {
                bh8 bhv = *(const bh8*)&kh[n * 16 + t15][ks * 32 + t4 * 8];
                bh8 blv = *(const bh8*)&kl[n * 16 + t15][ks * 32 + t4 * 8];
                s[n] = __builtin_amdgcn_mfma_f32_16x16x32_bf16(qh[ks], bhv, s[n], 0, 0, 0);
                s[n] = __builtin_amdgcn_mfma_f32_16x16x32_bf16(qh[ks], blv, s[n], 0, 0, 0);
                s[n] = __builtin_amdgcn_mfma_f32_16x16x32_bf16(ql[ks], bhv, s[n], 0, 0, 0);
            }
        }

        // causal mask — only the diagonal tile (lives in the last chunk)
        if (sm && jt == qt) {
#pragma unroll
            for (int n = 0; n < 4; ++n) {
                const int col = n * 16 + t15;
#pragma unroll
                for (int r = 0; r < 4; ++r)
                    if (col > wid * 16 + t4 * 4 + r) s[n][r] = -INFINITY;
            }
        }

        // online softmax per row; stats across the 16-lane t15 groups
#pragma unroll
        for (int r = 0; r < 4; ++r) {
            float rm = fmaxf(fmaxf(s[0][r], s[1][r]), fmaxf(s[2][r], s[3][r]));
            rm = fmaxf(rm, __shfl_xor(rm, 1));
            rm = fmaxf(rm, __shfl_xor(rm, 2));
            rm = fmaxf(rm, __shfl_xor(rm, 4));
            rm = fmaxf(rm, __shfl_xor(rm, 8));
            const float mn = fmaxf(m_i[r], rm);
            const float cf = __expf(m_i[r] - mn);
            const float p0 = __expf(s[0][r] - mn);
            const float p1 = __expf(s[1][r] - mn);
            const float p2 = __expf(s[2][r] - mn);
            const float p3 = __expf(s[3][r] - mn);
            float rs = p0 + p1 + p2 + p3;
            rs += __shfl_xor(rs, 1);
            rs += __shfl_xor(rs, 2);
            rs += __shfl_xor(rs, 4);
            rs += __shfl_xor(rs, 8);
            l_i[r] = l_i[r] * cf + rs;
            m_i[r] = mn;
#pragma unroll
            for (int hs = 0; hs < 4; ++hs) o[hs][r] *= cf;
            ushort4 pw;
            pw.x = bf16rn(p0); pw.y = bf16rn(p1); pw.z = bf16rn(p2); pw.w = bf16rn(p3);
            *(ushort4*)&ps[wid * 16 + t4 * 4 + r][t15 * 4] = pw;
        }

        // O += P' V'  (permuted k-index matches vtp permutation)
#pragma unroll
        for (int ks = 0; ks < 2; ++ks) {
            bh8 pa = *(const bh8*)&ps[wid * 16 + t15][ks * 32 + t4 * 8];
#pragma unroll
            for (int hs = 0; hs < 4; ++hs) {
                bh8 bv = *(const bh8*)&vt[hs * 16 + t15][ks * 32 + t4 * 8];
                o[hs] = __builtin_amdgcn_mfma_f32_16x16x32_bf16(pa, bv, o[hs], 0, 0, 0);
            }
        }
    }

    if (nch == 1) {
        // final: normalize + write fp32
#pragma unroll
        for (int r = 0; r < 4; ++r) {
            const float inv = 1.0f / l_i[r];
            const size_t rowoff = (bb + qs + wid * 16 + t4 * 4 + r) * NH;
#pragma unroll
            for (int hs = 0; hs < 4; ++hs)
                out[rowoff + hs * 16 + t15] = o[hs][r] * inv;
        }
    } else {
        // partial: unnormalized o + per-row (m, l)
        const int slot = (b * 24 + (qt - 8)) * 4 + c;
        float* pop = po + (size_t)slot * 64 * 64;
#pragma unroll
        for (int r = 0; r < 4; ++r) {
            const int rl = wid * 16 + t4 * 4 + r;
#pragma unroll
            for (int hs = 0; hs < 4; ++hs)
                pop[(size_t)rl * 64 + hs * 16 + t15] = o[hs][r];
            if (t15 == 0) {
                pm[(size_t)slot * 64 + rl] = m_i[r];
                pl[(size_t)slot * 64 + rl] = l_i[r];
            }
        }
    }
}

// ---------------- Kernel 3: combine KV-split partials ------------------------
// grid (24, 8) x 256 thr: (b, qt>=8). Exact online-softmax merge.
__global__ void attn_combine(const float* __restrict__ po, const float* __restrict__ pm,
                             const float* __restrict__ pl, float* __restrict__ out)
{
    const int qt  = 8 + (int)blockIdx.x;
    const int b   = blockIdx.y;
    const int nch = (qt + 8) >> 3;
    const int tid = threadIdx.x;
    const int r   = tid >> 2;              // 0..63
    const int h0  = (tid & 3) * 16;        // 16 h per thread
    const int base = (b * 24 + (qt - 8)) * 4;

    float m[4], w[4];
    float M = -INFINITY;
#pragma unroll
    for (int cc = 0; cc < 4; ++cc) {
        m[cc] = (cc < nch) ? pm[(size_t)(base + cc) * 64 + r] : -INFINITY;
        M = fmaxf(M, m[cc]);
    }
    float denom = 0.f;
#pragma unroll
    for (int cc = 0; cc < 4; ++cc) {
        w[cc] = (cc < nch) ? __expf(m[cc] - M) : 0.f;
        denom += ((cc < nch) ? pl[(size_t)(base + cc) * 64 + r] : 0.f) * w[cc];
    }
    const float inv = 1.0f / denom;

    const size_t orow = ((size_t)b * NT + (size_t)qt * 64 + r) * NH;
#pragma unroll
    for (int v = 0; v < 4; ++v) {
        float4 acc = make_float4(0.f, 0.f, 0.f, 0.f);
#pragma unroll
        for (int cc = 0; cc < 4; ++cc) {
            if (cc < nch) {
                float4 pv = *(const float4*)(po + ((size_t)(base + cc) * 64 + r) * 64 + h0 + v * 4);
                acc.x += pv.x * w[cc]; acc.y += pv.y * w[cc];
                acc.z += pv.z * w[cc]; acc.w += pv.w * w[cc];
            }
        }
        acc.x *= inv; acc.y *= inv; acc.z *= inv; acc.w *= inv;
        *(float4*)(out + orow + h0 + v * 4) = acc;
    }
}

extern "C" void kernel_launch(void* const* d_in, const int* in_sizes, int n_in,
                              void* d_out, int out_size, void* d_ws, size_t ws_size,
                              hipStream_t stream)
{
    const float* x  = (const float*)d_in[0];
    const float* wq = (const float*)d_in[1];
    const float* wk = (const float*)d_in[2];
    const float* wv = (const float*)d_in[3];
    const int*   sm = (const int*)d_in[4];
    float* out = (float*)d_out;

    u16* whi = (u16*)d_ws;                       // [192][1024]
    u16* wlo = whi + (size_t)192 * NE;
    u16* qhi = wlo + (size_t)192 * NE;           // [B*T][64] each below
    u16* qlo = qhi + (size_t)NB * NT * NH;
    u16* khi = qlo + (size_t)NB * NT * NH;
    u16* klo = khi + (size_t)NB * NT * NH;
    u16* vtp = klo + (size_t)NB * NT * NH;       // [B][64][2048] permuted
    float* po = (float*)(vtp + (size_t)NB * NT * NH);  // [8*24*4][64][64]
    float* pm = po + (size_t)NB * 24 * 4 * 64 * 64;    // [8*24*4][64]
    float* pl = pm + (size_t)NB * 24 * 4 * 64;

    wprep<<<dim3(192), 256, 0, stream>>>(wq, wk, wv, whi, wlo);
    qkv_mfma<<<dim3((NB * NT) / 32), 256, 0, stream>>>(x, whi, wlo, qhi, qlo, khi, klo, vtp);
    attn_mfma<<<dim3(80, NB), 256, 0, stream>>>(qhi, qlo, khi, klo, vtp, sm, out, po, pm, pl);
    attn_combine<<<dim3(24, NB), 256, 0, stream>>>(po, pm, pl, out);
}

// Round 4
// 159.497 us; speedup vs baseline: 2.4438x; 1.0558x over previous
//
#include <hip/hip_runtime.h>
#include <math.h>

#define NB 8
#define NT 2048
#define NE 1024
#define NH 64

typedef __attribute__((ext_vector_type(8))) short bh8;   // 8 x bf16 bits
typedef __attribute__((ext_vector_type(4))) float f4;    // MFMA accumulator

typedef unsigned short u16;

__device__ __forceinline__ u16 bf16rn(float f) {
    unsigned u = __float_as_uint(f);
    u += 0x7FFFu + ((u >> 16) & 1u);      // round-to-nearest-even
    return (u16)(u >> 16);
}
__device__ __forceinline__ float bf16f(u16 h) {
    return __uint_as_float(((unsigned)h) << 16);
}
// 16B-quad XOR swizzle within a 64-u16 (128B) row: returns u16 offset of quad start
__device__ __forceinline__ int swzq(int quad, int row) {
    return ((quad ^ (row & 7)) << 3);
}

// ---------------- Kernel 0: W -> (hi, lo) bf16, [192][1024], pre-swizzled ---
__global__ void wprep(const float* __restrict__ wq, const float* __restrict__ wk,
                      const float* __restrict__ wv,
                      u16* __restrict__ whi, u16* __restrict__ wlo)
{
    const int row = blockIdx.x;                       // 0..191
    const int k0  = threadIdx.x * 4;
    const float* src = (row < 64)  ? (wq + (size_t)row * NE)
                     : (row < 128) ? (wk + (size_t)(row - 64) * NE)
                     :               (wv + (size_t)(row - 128) * NE);
    float4 v = *(const float4*)(src + k0);
    ushort4 h, l;
    h.x = bf16rn(v.x); l.x = bf16rn(v.x - bf16f(h.x));
    h.y = bf16rn(v.y); l.y = bf16rn(v.y - bf16f(h.y));
    h.z = bf16rn(v.z); l.z = bf16rn(v.z - bf16f(h.z));
    h.w = bf16rn(v.w); l.w = bf16rn(v.w - bf16f(h.w));
    const int c   = k0 >> 6;                 // 64-col chunk
    const int kk  = k0 & 63;
    const int pos = c * 64 + swzq(kk >> 3, row) + (kk & 7);
    *(ushort4*)(whi + (size_t)row * NE + pos) = h;
    *(ushort4*)(wlo + (size_t)row * NE + pos) = l;
}

// ---------------- Kernel 1: QKV projection via split-bf16 MFMA ---------------
// 512 blocks x 256 thr. Block: 32 rows x 192 cols, BK=64.
// Wave w: cols [48w,48w+48). C = xh*wh + xh*wl + xl*wh.
// LDS swizzled (quad ^ row&7) -> conflict-free b128 fragment reads.
__global__ __launch_bounds__(256, 2) void qkv_mfma(
    const float* __restrict__ x, const u16* __restrict__ whi_, const u16* __restrict__ wlo_,
    u16* __restrict__ qhi, u16* __restrict__ qlo,
    u16* __restrict__ khi, u16* __restrict__ klo, u16* __restrict__ vtp)
{
    __shared__ u16 xh[32][64], xl[32][64];     // 8 KB
    __shared__ u16 wh[192][64], wl[192][64];   // 48 KB

    const int tid  = threadIdx.x;
    const int wid  = tid >> 6;
    const int lane = tid & 63;
    const int t15  = lane & 15, t4 = lane >> 4;
    const int row0 = blockIdx.x * 32;

    const f4 fzero = {0.f, 0.f, 0.f, 0.f};
    f4 acc[2][3];
#pragma unroll
    for (int m = 0; m < 2; ++m)
#pragma unroll
        for (int n = 0; n < 3; ++n) acc[m][n] = fzero;

    for (int kt = 0; kt < NE; kt += 64) {
        __syncthreads();
        // stage X tile (32x64 fp32 -> hi/lo bf16), swizzled half-quad writes
#pragma unroll
        for (int it = 0; it < 2; ++it) {
            const int f = tid + it * 256;
            const int r = f >> 4, k0 = (f & 15) * 4;
            float4 v = *(const float4*)(x + (size_t)(row0 + r) * NE + kt + k0);
            ushort4 h, l;
            h.x = bf16rn(v.x); l.x = bf16rn(v.x - bf16f(h.x));
            h.y = bf16rn(v.y); l.y = bf16rn(v.y - bf16f(h.y));
            h.z = bf16rn(v.z); l.z = bf16rn(v.z - bf16f(h.z));
            h.w = bf16rn(v.w); l.w = bf16rn(v.w - bf16f(h.w));
            const int pos = swzq(k0 >> 3, r) + (k0 & 7);
            *(ushort4*)&xh[r][pos] = h;
            *(ushort4*)&xl[r][pos] = l;
        }
        // stage W tile (192x64, pre-swizzled in global): linear uint4 copies
#pragma unroll
        for (int it = 0; it < 6; ++it) {
            const int f = tid + it * 256;
            const int r = f >> 3, sg = f & 7;
            *(uint4*)&wh[r][sg * 8] = *(const uint4*)(whi_ + (size_t)r * NE + kt + sg * 8);
            *(uint4*)&wl[r][sg * 8] = *(const uint4*)(wlo_ + (size_t)r * NE + kt + sg * 8);
        }
        __syncthreads();

#pragma unroll
        for (int ks = 0; ks < 2; ++ks) {
            const int quad = 4 * ks + t4;
            bh8 ah[2], al[2];
#pragma unroll
            for (int m = 0; m < 2; ++m) {
                const int r = m * 16 + t15;
                ah[m] = *(const bh8*)&xh[r][swzq(quad, r)];
                al[m] = *(const bh8*)&xl[r][swzq(quad, r)];
            }
#pragma unroll
            for (int n = 0; n < 3; ++n) {
                const int c = wid * 48 + n * 16 + t15;
                bh8 bhv = *(const bh8*)&wh[c][swzq(quad, c)];
                bh8 blv = *(const bh8*)&wl[c][swzq(quad, c)];
#pragma unroll
                for (int m = 0; m < 2; ++m) {
                    acc[m][n] = __builtin_amdgcn_mfma_f32_16x16x32_bf16(ah[m], bhv, acc[m][n], 0, 0, 0);
                    acc[m][n] = __builtin_amdgcn_mfma_f32_16x16x32_bf16(ah[m], blv, acc[m][n], 0, 0, 0);
                    acc[m][n] = __builtin_amdgcn_mfma_f32_16x16x32_bf16(al[m], bhv, acc[m][n], 0, 0, 0);
                }
            }
        }
    }

    // epilogue: D layout col=lane&15, row=(lane>>4)*4+reg; outputs pre-swizzled
#pragma unroll
    for (int m = 0; m < 2; ++m) {
#pragma unroll
        for (int n = 0; n < 3; ++n) {
            const int col = wid * 48 + n * 16 + t15;
#pragma unroll
            for (int r = 0; r < 4; ++r) {
                const int row = row0 + m * 16 + t4 * 4 + r;
                float v = acc[m][n][r];
                if (col < 64) {
                    v *= 8.0f;                         // sqrt(head_size) folded into q
                    const u16 h = bf16rn(v);
                    const int pos = swzq(col >> 3, row) + (col & 7);
                    qhi[(size_t)row * NH + pos] = h;
                    qlo[(size_t)row * NH + pos] = bf16rn(v - bf16f(h));
                } else if (col < 128) {
                    const int cc  = col - 64;
                    const u16 h = bf16rn(v);
                    const int pos = swzq(cc >> 3, row) + (cc & 7);
                    khi[(size_t)row * NH + pos] = h;
                    klo[(size_t)row * NH + pos] = bf16rn(v - bf16f(h));
                } else {
                    const int hh  = col - 128;         // head dim
                    const int b   = row >> 11;
                    const int tok = row & (NT - 1);
                    const int c   = tok & 63;
                    const int p   = (c & 15) * 4 + (c >> 4);         // PV permutation
                    const int tp  = (tok & ~63) | (swzq(p >> 3, hh) + (p & 7));
                    vtp[((size_t)b * NH + hh) * NT + tp] = bf16rn(v);
                }
            }
        }
    }
}

// ---------------- Kernel 2: MFMA flash attention, KV-split -------------------
// grid (80, 8) x 256 thr. q-tile 64 (wave w: rows 16w..16w+15), kv-tile 64.
// Per (b,qt): nch=(qt+8)/8 chunks, one block each. All LDS quad-swizzled.
__global__ __launch_bounds__(256, 2) void attn_mfma(
    const u16* __restrict__ qhi, const u16* __restrict__ qlo,
    const u16* __restrict__ khi, const u16* __restrict__ klo,
    const u16* __restrict__ vtp, const int* __restrict__ smp,
    float* __restrict__ out,
    float* __restrict__ po, float* __restrict__ pm, float* __restrict__ pl)
{
    __shared__ u16 kh[64][64], kl[64][64], vt[64][64], ps[64][64];  // 32 KB

    const int tid  = threadIdx.x;
    const int wid  = tid >> 6;
    const int lane = tid & 63;
    const int t15  = lane & 15, t4 = lane >> 4;
    const int b    = blockIdx.y;
    const int u    = 79 - (int)blockIdx.x;       // heavy chunks dispatch first
    int qt, c;
    if (u < 8)       { qt = u;                   c = 0; }
    else if (u < 24) { qt = 8  + ((u - 8) >> 1); c = (u - 8) & 1; }
    else if (u < 48) { qt = 16 + (u - 24) / 3;   c = (u - 24) % 3; }
    else             { qt = 24 + ((u - 48) >> 2); c = (u - 48) & 3; }
    const int nch   = (qt + 8) >> 3;
    const int sm    = smp[0];
    const int total = sm ? (qt + 1) : (NT / 64);
    const int jt0   = c * total / nch;
    const int jt1   = (c + 1) * total / nch;
    const int qs    = qt * 64;

    const size_t bb = (size_t)b * NT;

    // hoist Q fragments from pre-swizzled global (row&7 == t15&7)
    bh8 qh[2], ql[2];
#pragma unroll
    for (int ks = 0; ks < 2; ++ks) {
        const size_t off = (bb + qs + wid * 16 + t15) * NH + swzq(4 * ks + t4, t15);
        qh[ks] = *(const bh8*)(qhi + off);
        ql[ks] = *(const bh8*)(qlo + off);
    }

    const f4 fzero = {0.f, 0.f, 0.f, 0.f};
    f4 o[4];
    float m_i[4], l_i[4];
#pragma unroll
    for (int i = 0; i < 4; ++i) { o[i] = fzero; m_i[i] = -INFINITY; l_i[i] = 0.f; }

    for (int jt = jt0; jt < jt1; ++jt) {
        const int js = jt * 64;
        __syncthreads();                       // prev iter done with kh/kl/vt/ps
        // stage K hi/lo + V^T (pre-swizzled in global): linear uint4 copies
#pragma unroll
        for (int it = 0; it < 2; ++it) {
            const int f = tid + it * 256;
            const int r = f >> 3, sg = f & 7;
            *(uint4*)&kh[r][sg * 8] = *(const uint4*)(khi + (bb + js + r) * NH + sg * 8);
            *(uint4*)&kl[r][sg * 8] = *(const uint4*)(klo + (bb + js + r) * NH + sg * 8);
            *(uint4*)&vt[r][sg * 8] = *(const uint4*)(vtp + ((size_t)b * NH + r) * NT + js + sg * 8);
        }
        __syncthreads();

        // S = (8q) k^T (split)
        f4 s[4];
#pragma unroll
        for (int n = 0; n < 4; ++n) s[n] = fzero;
#pragma unroll
        for (int n = 0; n < 4; ++n) {
#pragma unroll
            for (int ks = 0; ks < 2; ++ks) {
                const int rr = n * 16 + t15;
                bh8 bhv = *(const bh8*)&kh[rr][swzq(4 * ks + t4, rr)];
                bh8 blv = *(const bh8*)&kl[rr][swzq(4 * ks + t4, rr)];
                s[n] = __builtin_amdgcn_mfma_f32_16x16x32_bf16(qh[ks], bhv, s[n], 0, 0, 0);
                s[n] = __builtin_amdgcn_mfma_f32_16x16x32_bf16(qh[ks], blv, s[n], 0, 0, 0);
                s[n] = __builtin_amdgcn_mfma_f32_16x16x32_bf16(ql[ks], bhv, s[n], 0, 0, 0);
            }
        }

        // causal mask — only the diagonal tile (in the last chunk)
        if (sm && jt == qt) {
#pragma unroll
            for (int n = 0; n < 4; ++n) {
                const int col = n * 16 + t15;
#pragma unroll
                for (int r = 0; r < 4; ++r)
                    if (col > wid * 16 + t4 * 4 + r) s[n][r] = -INFINITY;
            }
        }

        // online softmax per row; stats across the 16-lane t15 groups
#pragma unroll
        for (int r = 0; r < 4; ++r) {
            float rm = fmaxf(fmaxf(s[0][r], s[1][r]), fmaxf(s[2][r], s[3][r]));
            rm = fmaxf(rm, __shfl_xor(rm, 1));
            rm = fmaxf(rm, __shfl_xor(rm, 2));
            rm = fmaxf(rm, __shfl_xor(rm, 4));
            rm = fmaxf(rm, __shfl_xor(rm, 8));
            const float mn = fmaxf(m_i[r], rm);
            const float cf = __expf(m_i[r] - mn);
            const float p0 = __expf(s[0][r] - mn);
            const float p1 = __expf(s[1][r] - mn);
            const float p2 = __expf(s[2][r] - mn);
            const float p3 = __expf(s[3][r] - mn);
            float rs = p0 + p1 + p2 + p3;
            rs += __shfl_xor(rs, 1);
            rs += __shfl_xor(rs, 2);
            rs += __shfl_xor(rs, 4);
            rs += __shfl_xor(rs, 8);
            l_i[r] = l_i[r] * cf + rs;
            m_i[r] = mn;
#pragma unroll
            for (int hs = 0; hs < 4; ++hs) o[hs][r] *= cf;
            ushort4 pw;
            pw.x = bf16rn(p0); pw.y = bf16rn(p1); pw.z = bf16rn(p2); pw.w = bf16rn(p3);
            const int R = wid * 16 + t4 * 4 + r;
            *(ushort4*)&ps[R][swzq(t15 >> 1, R) + (t15 & 1) * 4] = pw;
        }

        // O += P' V'  (permuted k-index matches vtp permutation)
#pragma unroll
        for (int ks = 0; ks < 2; ++ks) {
            const int pr = wid * 16 + t15;
            bh8 pa = *(const bh8*)&ps[pr][swzq(4 * ks + t4, pr)];
#pragma unroll
            for (int hs = 0; hs < 4; ++hs) {
                const int vr = hs * 16 + t15;
                bh8 bv = *(const bh8*)&vt[vr][swzq(4 * ks + t4, vr)];
                o[hs] = __builtin_amdgcn_mfma_f32_16x16x32_bf16(pa, bv, o[hs], 0, 0, 0);
            }
        }
    }

    if (nch == 1) {
        // final: normalize + write fp32
#pragma unroll
        for (int r = 0; r < 4; ++r) {
            const float inv = 1.0f / l_i[r];
            const size_t rowoff = (bb + qs + wid * 16 + t4 * 4 + r) * NH;
#pragma unroll
            for (int hs = 0; hs < 4; ++hs)
                out[rowoff + hs * 16 + t15] = o[hs][r] * inv;
        }
    } else {
        // partial: unnormalized o + per-row (m, l)
        const int slot = (b * 24 + (qt - 8)) * 4 + c;
        float* pop = po + (size_t)slot * 64 * 64;
#pragma unroll
        for (int r = 0; r < 4; ++r) {
            const int rl = wid * 16 + t4 * 4 + r;
#pragma unroll
            for (int hs = 0; hs < 4; ++hs)
                pop[(size_t)rl * 64 + hs * 16 + t15] = o[hs][r];
            if (t15 == 0) {
                pm[(size_t)slot * 64 + rl] = m_i[r];
                pl[(size_t)slot * 64 + rl] = l_i[r];
            }
        }
    }
}

// ---------------- Kernel 3: combine KV-split partials ------------------------
__global__ void attn_combine(const float* __restrict__ po, const float* __restrict__ pm,
                             const float* __restrict__ pl, float* __restrict__ out)
{
    const int qt  = 8 + (int)blockIdx.x;
    const int b   = blockIdx.y;
    const int nch = (qt + 8) >> 3;
    const int tid = threadIdx.x;
    const int r   = tid >> 2;              // 0..63
    const int h0  = (tid & 3) * 16;        // 16 h per thread
    const int base = (b * 24 + (qt - 8)) * 4;

    float m[4], w[4];
    float M = -INFINITY;
#pragma unroll
    for (int cc = 0; cc < 4; ++cc) {
        m[cc] = (cc < nch) ? pm[(size_t)(base + cc) * 64 + r] : -INFINITY;
        M = fmaxf(M, m[cc]);
    }
    float denom = 0.f;
#pragma unroll
    for (int cc = 0; cc < 4; ++cc) {
        w[cc] = (cc < nch) ? __expf(m[cc] - M) : 0.f;
        denom += ((cc < nch) ? pl[(size_t)(base + cc) * 64 + r] : 0.f) * w[cc];
    }
    const float inv = 1.0f / denom;

    const size_t orow = ((size_t)b * NT + (size_t)qt * 64 + r) * NH;
#pragma unroll
    for (int v = 0; v < 4; ++v) {
        float4 acc = make_float4(0.f, 0.f, 0.f, 0.f);
#pragma unroll
        for (int cc = 0; cc < 4; ++cc) {
            if (cc < nch) {
                float4 pv = *(const float4*)(po + ((size_t)(base + cc) * 64 + r) * 64 + h0 + v * 4);
                acc.x += pv.x * w[cc]; acc.y += pv.y * w[cc];
                acc.z += pv.z * w[cc]; acc.w += pv.w * w[cc];
            }
        }
        acc.x *= inv; acc.y *= inv; acc.z *= inv; acc.w *= inv;
        *(float4*)(out + orow + h0 + v * 4) = acc;
    }
}

extern "C" void kernel_launch(void* const* d_in, const int* in_sizes, int n_in,
                              void* d_out, int out_size, void* d_ws, size_t ws_size,
                              hipStream_t stream)
{
    const float* x  = (const float*)d_in[0];
    const float* wq = (const float*)d_in[1];
    const float* wk = (const float*)d_in[2];
    const float* wv = (const float*)d_in[3];
    const int*   sm = (const int*)d_in[4];
    float* out = (float*)d_out;

    u16* whi = (u16*)d_ws;                       // [192][1024] (swizzled)
    u16* wlo = whi + (size_t)192 * NE;
    u16* qhi = wlo + (size_t)192 * NE;           // [B*T][64] each (swizzled)
    u16* qlo = qhi + (size_t)NB * NT * NH;
    u16* khi = qlo + (size_t)NB * NT * NH;
    u16* klo = khi + (size_t)NB * NT * NH;
    u16* vtp = klo + (size_t)NB * NT * NH;       // [B][64][2048] perm+swizzled
    float* po = (float*)(vtp + (size_t)NB * NT * NH);  // [8*24*4][64][64]
    float* pm = po + (size_t)NB * 24 * 4 * 64 * 64;    // [8*24*4][64]
    float* pl = pm + (size_t)NB * 24 * 4 * 64;

    wprep<<<dim3(192), 256, 0, stream>>>(wq, wk, wv, whi, wlo);
    qkv_mfma<<<dim3((NB * NT) / 32), 256, 0, stream>>>(x, whi, wlo, qhi, qlo, khi, klo, vtp);
    attn_mfma<<<dim3(80, NB), 256, 0, stream>>>(qhi, qlo, khi, klo, vtp, sm, out, po, pm, pl);
    attn_combine<<<dim3(24, NB), 256, 0, stream>>>(po, pm, pl, out);
}